// Round 1
// baseline (420.727 us; speedup 1.0000x reference)
//
#include <hip/hip_runtime.h>

#define B_ 128
#define A_ 64
#define D_ 256
#define K_ 2048
#define R_ (B_*A_)   // 8192

// ---------------- utility ----------------
__device__ inline float waveReduceSum(float v) {
    #pragma unroll
    for (int off = 32; off > 0; off >>= 1)
        v += __shfl_down(v, off, 64);
    return v;
}

// ---------------- row squared norms (+ optional total accumulate) ----------------
// one wave per row of D_=256 floats; 4 waves per block
__global__ void row_sqnorm(const float* __restrict__ X, float* __restrict__ out,
                           double* __restrict__ tot, int rows) {
    int wave = threadIdx.x >> 6;
    int lane = threadIdx.x & 63;
    int row  = blockIdx.x * 4 + wave;
    if (row >= rows) return;
    float4 v = *reinterpret_cast<const float4*>(X + (size_t)row * D_ + lane * 4);
    float s = v.x*v.x + v.y*v.y + v.z*v.z + v.w*v.w;
    s = waveReduceSum(s);
    if (lane == 0) {
        out[row] = s;
        if (tot) atomicAdd(tot, (double)s);
    }
}

// ---------------- latent diversity: sum_a ||sum_i x[i,a,:]||^2 ----------------
__global__ void col_sum_sq(const float* __restrict__ X, double* __restrict__ acc) {
    int idx = blockIdx.x * blockDim.x + threadIdx.x;   // a*D_ + d, 0..A_*D_-1
    float s = 0.f;
    #pragma unroll 4
    for (int i = 0; i < B_; ++i) s += X[(size_t)i * (A_*D_) + idx];
    float p = s * s;
    __shared__ float red[256];
    red[threadIdx.x] = p; __syncthreads();
    for (int off = 128; off > 0; off >>= 1) {
        if (threadIdx.x < off) red[threadIdx.x] += red[threadIdx.x + off];
        __syncthreads();
    }
    if (threadIdx.x == 0) atomicAdd(acc, (double)red[0]);
}

// ---------------- weights total (single block) ----------------
__global__ void wsum_kernel(const float* __restrict__ w, double* __restrict__ acc) {
    double s = 0.0;
    for (int i = threadIdx.x; i < K_; i += 256) s += (double)w[i];
    __shared__ double red[256];
    red[threadIdx.x] = s; __syncthreads();
    for (int off = 128; off > 0; off >>= 1) {
        if (threadIdx.x < off) red[threadIdx.x] += red[threadIdx.x + off];
        __syncthreads();
    }
    if (threadIdx.x == 0) acc[2] = red[0];
}

// ---------------- uselessness ----------------
__global__ void useless_kernel(const float* __restrict__ X, const float* __restrict__ C,
                               const float* __restrict__ w, const int* __restrict__ ridx,
                               const double* __restrict__ acc_in, double* __restrict__ use_acc) {
    int wave = threadIdx.x >> 6, lane = threadIdx.x & 63;
    int k = blockIdx.x * 4 + wave;
    if (k >= K_) return;
    float cutoff = (float)(acc_in[2] / (100.0 * (double)K_));
    if (!(w[k] < cutoff)) return;
    int r = ridx[k];
    float4 xv = *reinterpret_cast<const float4*>(X + (size_t)r * D_ + lane * 4);
    float4 cv = *reinterpret_cast<const float4*>(C + (size_t)k * D_ + lane * 4);
    float s = logf(fabsf(xv.x - cv.x) + 1.f) + logf(fabsf(xv.y - cv.y) + 1.f)
            + logf(fabsf(xv.z - cv.z) + 1.f) + logf(fabsf(xv.w - cv.w) + 1.f);
    s = waveReduceSum(s);
    if (lane == 0) atomicAdd(use_acc, (double)s);
}

// ---------------- distance GEMM: dist = xsq + csq - 2 * X.C^T ----------------
#define BM 64
#define BN 64
#define BK 16
__global__ __launch_bounds__(256) void dist_gemm(const float* __restrict__ X, const float* __restrict__ C,
                                                 const float* __restrict__ xsq, const float* __restrict__ csq,
                                                 float* __restrict__ Dist) {
    __shared__ float As[BK][BM + 1];
    __shared__ float Bs[BK][BN + 1];
    int tx = threadIdx.x & 15, ty = threadIdx.x >> 4;
    int bm0 = blockIdx.y * BM, bn0 = blockIdx.x * BN;
    int lr = threadIdx.x >> 2;          // 0..63: row within tile
    int lc = (threadIdx.x & 3) * 4;     // 0,4,8,12
    float acc[4][4] = {};
    for (int k0 = 0; k0 < D_; k0 += BK) {
        float4 av = *reinterpret_cast<const float4*>(X + (size_t)(bm0 + lr) * D_ + k0 + lc);
        float4 bv = *reinterpret_cast<const float4*>(C + (size_t)(bn0 + lr) * D_ + k0 + lc);
        As[lc+0][lr] = av.x; As[lc+1][lr] = av.y; As[lc+2][lr] = av.z; As[lc+3][lr] = av.w;
        Bs[lc+0][lr] = bv.x; Bs[lc+1][lr] = bv.y; Bs[lc+2][lr] = bv.z; Bs[lc+3][lr] = bv.w;
        __syncthreads();
        #pragma unroll
        for (int kk = 0; kk < BK; ++kk) {
            float a[4], b[4];
            #pragma unroll
            for (int i = 0; i < 4; ++i) a[i] = As[kk][ty*4 + i];
            #pragma unroll
            for (int j = 0; j < 4; ++j) b[j] = Bs[kk][tx*4 + j];
            #pragma unroll
            for (int i = 0; i < 4; ++i)
                #pragma unroll
                for (int j = 0; j < 4; ++j)
                    acc[i][j] += a[i] * b[j];
        }
        __syncthreads();
    }
    #pragma unroll
    for (int i = 0; i < 4; ++i) {
        int row = bm0 + ty*4 + i;
        float xs = xsq[row];
        #pragma unroll
        for (int j = 0; j < 4; ++j) {
            int col = bn0 + tx*4 + j;
            Dist[(size_t)row * K_ + col] = xs + csq[col] - 2.f * acc[i][j];
        }
    }
}

// ---------------- softmax + argmin per row (in place on Dist) ----------------
__global__ __launch_bounds__(256) void softmax_argmin(float* __restrict__ Dist, int* __restrict__ amin) {
    __shared__ float rv[256];
    __shared__ int   ri[256];
    int row = blockIdx.x;
    float* drow = Dist + (size_t)row * K_;
    int t = threadIdx.x;
    float v[8];
    float4 v0 = *reinterpret_cast<const float4*>(drow + t*8);
    float4 v1 = *reinterpret_cast<const float4*>(drow + t*8 + 4);
    v[0]=v0.x; v[1]=v0.y; v[2]=v0.z; v[3]=v0.w;
    v[4]=v1.x; v[5]=v1.y; v[6]=v1.z; v[7]=v1.w;
    // local min with first-index tiebreak (chunk is contiguous -> strict < keeps first)
    float bv = v[0]; int bi = t*8;
    #pragma unroll
    for (int j = 1; j < 8; ++j) if (v[j] < bv) { bv = v[j]; bi = t*8 + j; }
    rv[t] = bv; ri[t] = bi; __syncthreads();
    for (int off = 128; off > 0; off >>= 1) {
        if (t < off) {
            float ov = rv[t+off]; int oi = ri[t+off];
            if (ov < rv[t] || (ov == rv[t] && oi < ri[t])) { rv[t] = ov; ri[t] = oi; }
        }
        __syncthreads();
    }
    float dmin = rv[0];
    if (t == 0) amin[row] = ri[0];
    __syncthreads();
    // exp and sum
    float e[8]; float s = 0.f;
    #pragma unroll
    for (int j = 0; j < 8; ++j) { e[j] = expf(-100.f * (v[j] - dmin)); s += e[j]; }
    rv[t] = s; __syncthreads();
    for (int off = 128; off > 0; off >>= 1) {
        if (t < off) rv[t] += rv[t + off];
        __syncthreads();
    }
    float inv = 1.f / rv[0];
    float4 o0 = make_float4(e[0]*inv, e[1]*inv, e[2]*inv, e[3]*inv);
    float4 o1 = make_float4(e[4]*inv, e[5]*inv, e[6]*inv, e[7]*inv);
    *reinterpret_cast<float4*>(drow + t*8)     = o0;
    *reinterpret_cast<float4*>(drow + t*8 + 4) = o1;
}

// ---------------- quantized output + quantization loss ----------------
__global__ void quantize_kernel(const float* __restrict__ X, const float* __restrict__ C,
                                const int* __restrict__ amin, float* __restrict__ outq,
                                double* __restrict__ ql_acc) {
    int wave = threadIdx.x >> 6, lane = threadIdx.x & 63;
    int row = blockIdx.x * 4 + wave;
    int kk = amin[row];
    float4 q = *reinterpret_cast<const float4*>(C + (size_t)kk * D_ + lane * 4);
    float4 x = *reinterpret_cast<const float4*>(X + (size_t)row * D_ + lane * 4);
    *reinterpret_cast<float4*>(outq + (size_t)row * D_ + lane * 4) = q;
    float dx = x.x - q.x, dy = x.y - q.y, dz = x.z - q.z, dw = x.w - q.w;
    float s = dx*dx + dy*dy + dz*dz + dw*dw;
    s = waveReduceSum(s);
    if (lane == 0) atomicAdd(ql_acc, (double)s);
}

// ---------------- probs fill ----------------
__global__ void probs_fill(float* __restrict__ p) {
    p[blockIdx.x * 256 + threadIdx.x] = 1.0f / (float)K_;
}

// ---------------- finalize scalars ----------------
__global__ void finalize_kernel(const double* __restrict__ acc, float* __restrict__ o) {
    // acc: 0 xsq_total, 1 sa_sq_total, 2 w_total, 3 use_sum, 4 ql_sum
    o[0] = (float)(acc[4] / (double)R_);                                   // quantization_loss
    o[1] = (float)(acc[3] / (double)K_);                                   // uselessness
    o[2] = (float)(2.0 * acc[0] / (double)R_
                 - 2.0 * acc[1] / ((double)B_ * (double)B_ * (double)A_)); // latent_diversity
}

extern "C" void kernel_launch(void* const* d_in, const int* in_sizes, int n_in,
                              void* d_out, int out_size, void* d_ws, size_t ws_size,
                              hipStream_t stream) {
    const float* X  = (const float*)d_in[0];   // (B,A,D)
    const float* C  = (const float*)d_in[1];   // (K,D)
    const float* W  = (const float*)d_in[2];   // (K,)
    const int*   RI = (const int*)d_in[3];     // (K,)

    float* out    = (float*)d_out;
    float* out_q  = out;                         // R_*D_
    float* out_p  = out_q + (size_t)R_ * D_;     // R_
    float* out_s  = out_p + R_;                  // R_*K_ (also used as distance scratch)
    float* out_sc = out_s + (size_t)R_ * K_;     // 3 scalars

    double* acc = (double*)d_ws;                 // 5 doubles
    float*  xsq = (float*)((char*)d_ws + 64);    // R_
    float*  csq = xsq + R_;                      // K_
    int*    amin = (int*)(csq + K_);             // R_

    hipMemsetAsync(d_ws, 0, 64, stream);

    hipLaunchKernelGGL(row_sqnorm, dim3(R_/4), dim3(256), 0, stream, X, xsq, acc + 0, R_);
    hipLaunchKernelGGL(row_sqnorm, dim3(K_/4), dim3(256), 0, stream, C, csq, (double*)nullptr, K_);
    hipLaunchKernelGGL(col_sum_sq, dim3((A_*D_)/256), dim3(256), 0, stream, X, acc + 1);
    hipLaunchKernelGGL(wsum_kernel, dim3(1), dim3(256), 0, stream, W, acc);
    hipLaunchKernelGGL(useless_kernel, dim3(K_/4), dim3(256), 0, stream, X, C, W, RI, acc, acc + 3);
    hipLaunchKernelGGL(dist_gemm, dim3(K_/BN, R_/BM), dim3(256), 0, stream, X, C, xsq, csq, out_s);
    hipLaunchKernelGGL(softmax_argmin, dim3(R_), dim3(256), 0, stream, out_s, amin);
    hipLaunchKernelGGL(quantize_kernel, dim3(R_/4), dim3(256), 0, stream, X, C, amin, out_q, acc + 4);
    hipLaunchKernelGGL(probs_fill, dim3(R_/256), dim3(256), 0, stream, out_p);
    hipLaunchKernelGGL(finalize_kernel, dim3(1), dim3(1), 0, stream, acc, out_sc);
}

// Round 2
// 377.306 us; speedup vs baseline: 1.1151x; 1.1151x over previous
//
#include <hip/hip_runtime.h>

#define B_ 128
#define A_ 64
#define D_ 256
#define K_ 2048
#define R_ (B_*A_)   // 8192

// ---------------- utility ----------------
__device__ inline float waveReduceSum(float v) {
    #pragma unroll
    for (int off = 32; off > 0; off >>= 1)
        v += __shfl_down(v, off, 64);
    return v;
}

// ---------------- row squared norms (+ optional total accumulate) ----------------
__global__ void row_sqnorm(const float* __restrict__ X, float* __restrict__ out,
                           double* __restrict__ tot, int rows) {
    int wave = threadIdx.x >> 6;
    int lane = threadIdx.x & 63;
    int row  = blockIdx.x * 4 + wave;
    if (row >= rows) return;
    float4 v = *reinterpret_cast<const float4*>(X + (size_t)row * D_ + lane * 4);
    float s = v.x*v.x + v.y*v.y + v.z*v.z + v.w*v.w;
    s = waveReduceSum(s);
    if (lane == 0) {
        out[row] = s;
        if (tot) atomicAdd(tot, (double)s);
    }
}

// ---------------- latent diversity: sum_a ||sum_i x[i,a,:]||^2 ----------------
__global__ void col_sum_sq(const float* __restrict__ X, double* __restrict__ acc) {
    int idx = blockIdx.x * blockDim.x + threadIdx.x;   // a*D_ + d
    float s = 0.f;
    #pragma unroll 4
    for (int i = 0; i < B_; ++i) s += X[(size_t)i * (A_*D_) + idx];
    float p = s * s;
    p = waveReduceSum(p);
    __shared__ float red[4];
    int wave = threadIdx.x >> 6, lane = threadIdx.x & 63;
    if (lane == 0) red[wave] = p;
    __syncthreads();
    if (threadIdx.x == 0)
        atomicAdd(acc, (double)(red[0] + red[1] + red[2] + red[3]));
}

// ---------------- weights total (single block) ----------------
__global__ void wsum_kernel(const float* __restrict__ w, double* __restrict__ acc) {
    double s = 0.0;
    for (int i = threadIdx.x; i < K_; i += 256) s += (double)w[i];
    __shared__ double red[256];
    red[threadIdx.x] = s; __syncthreads();
    for (int off = 128; off > 0; off >>= 1) {
        if (threadIdx.x < off) red[threadIdx.x] += red[threadIdx.x + off];
        __syncthreads();
    }
    if (threadIdx.x == 0) acc[2] = red[0];
}

// ---------------- uselessness ----------------
__global__ void useless_kernel(const float* __restrict__ X, const float* __restrict__ C,
                               const float* __restrict__ w, const int* __restrict__ ridx,
                               const double* __restrict__ acc_in, double* __restrict__ use_acc) {
    int wave = threadIdx.x >> 6, lane = threadIdx.x & 63;
    int k = blockIdx.x * 4 + wave;
    if (k >= K_) return;
    float cutoff = (float)(acc_in[2] / (100.0 * (double)K_));
    if (!(w[k] < cutoff)) return;
    int r = ridx[k];
    float4 xv = *reinterpret_cast<const float4*>(X + (size_t)r * D_ + lane * 4);
    float4 cv = *reinterpret_cast<const float4*>(C + (size_t)k * D_ + lane * 4);
    float s = logf(fabsf(xv.x - cv.x) + 1.f) + logf(fabsf(xv.y - cv.y) + 1.f)
            + logf(fabsf(xv.z - cv.z) + 1.f) + logf(fabsf(xv.w - cv.w) + 1.f);
    s = waveReduceSum(s);
    if (lane == 0) atomicAdd(use_acc, (double)s);
}

// ---------------- distance GEMM: dist = xsq + csq - 2 * X.C^T ----------------
// 128x128 tile, 256 threads, 8x8 microtile as 2x2 groups of 4x4.
// LDS stride BM+4=132 -> bank = (4k + r) % 32:
//   writes (k fixed, r = 64 consecutive lanes) -> 2-way (free)
//   A reads (float4 @ 4*ty, ty 4 vals/wave, 16-lane broadcast) -> conflict-free
//   B reads (float4 @ 4*tx, tx 0..15) -> 2-way (free)
#define BM 128
#define BN 128
#define BK 16
__global__ __launch_bounds__(256, 4) void dist_gemm(
        const float* __restrict__ X, const float* __restrict__ C,
        const float* __restrict__ xsq, const float* __restrict__ csq,
        float* __restrict__ Dist) {
    __shared__ float As[BK][BM + 4];
    __shared__ float Bs[BK][BN + 4];
    int tid = threadIdx.x;
    int tx = tid & 15, ty = tid >> 4;          // 16x16 thread grid
    int bm0 = blockIdx.y * BM, bn0 = blockIdx.x * BN;

    // staging: threads 0..127 own A row (tid), 128..255 own B row (tid-128);
    // each thread loads its row's full BK=16 columns (64 B contiguous).
    int r = tid & 127;
    const float* src = (tid < 128) ? (X + (size_t)(bm0 + r) * D_)
                                   : (C + (size_t)(bn0 + r) * D_);
    float* dst = (tid < 128) ? &As[0][0] : &Bs[0][0];

    float acc[2][2][4][4] = {};

    float4 p0 = *reinterpret_cast<const float4*>(src + 0);
    float4 p1 = *reinterpret_cast<const float4*>(src + 4);
    float4 p2 = *reinterpret_cast<const float4*>(src + 8);
    float4 p3 = *reinterpret_cast<const float4*>(src + 12);

    for (int t = 0; t < D_ / BK; ++t) {
        __syncthreads();
        dst[ 0*(BM+4) + r] = p0.x; dst[ 1*(BM+4) + r] = p0.y;
        dst[ 2*(BM+4) + r] = p0.z; dst[ 3*(BM+4) + r] = p0.w;
        dst[ 4*(BM+4) + r] = p1.x; dst[ 5*(BM+4) + r] = p1.y;
        dst[ 6*(BM+4) + r] = p1.z; dst[ 7*(BM+4) + r] = p1.w;
        dst[ 8*(BM+4) + r] = p2.x; dst[ 9*(BM+4) + r] = p2.y;
        dst[10*(BM+4) + r] = p2.z; dst[11*(BM+4) + r] = p2.w;
        dst[12*(BM+4) + r] = p3.x; dst[13*(BM+4) + r] = p3.y;
        dst[14*(BM+4) + r] = p3.z; dst[15*(BM+4) + r] = p3.w;
        __syncthreads();
        if (t < D_ / BK - 1) {
            const float* s2 = src + (t + 1) * BK;
            p0 = *reinterpret_cast<const float4*>(s2 + 0);
            p1 = *reinterpret_cast<const float4*>(s2 + 4);
            p2 = *reinterpret_cast<const float4*>(s2 + 8);
            p3 = *reinterpret_cast<const float4*>(s2 + 12);
        }
        #pragma unroll
        for (int kk = 0; kk < BK; ++kk) {
            float4 a0 = *reinterpret_cast<const float4*>(&As[kk][ty * 4]);
            float4 a1 = *reinterpret_cast<const float4*>(&As[kk][64 + ty * 4]);
            float4 b0 = *reinterpret_cast<const float4*>(&Bs[kk][tx * 4]);
            float4 b1 = *reinterpret_cast<const float4*>(&Bs[kk][64 + tx * 4]);
            float af[2][4] = {{a0.x, a0.y, a0.z, a0.w}, {a1.x, a1.y, a1.z, a1.w}};
            float bf[2][4] = {{b0.x, b0.y, b0.z, b0.w}, {b1.x, b1.y, b1.z, b1.w}};
            #pragma unroll
            for (int rg = 0; rg < 2; ++rg)
                #pragma unroll
                for (int cg = 0; cg < 2; ++cg)
                    #pragma unroll
                    for (int i = 0; i < 4; ++i)
                        #pragma unroll
                        for (int j = 0; j < 4; ++j)
                            acc[rg][cg][i][j] += af[rg][i] * bf[cg][j];
        }
    }

    #pragma unroll
    for (int rg = 0; rg < 2; ++rg)
        #pragma unroll
        for (int i = 0; i < 4; ++i) {
            int row = bm0 + rg * 64 + ty * 4 + i;
            float xs = xsq[row];
            #pragma unroll
            for (int cg = 0; cg < 2; ++cg) {
                int col = bn0 + cg * 64 + tx * 4;
                float4 cs = *reinterpret_cast<const float4*>(csq + col);
                float4 o;
                o.x = xs + cs.x - 2.f * acc[rg][cg][i][0];
                o.y = xs + cs.y - 2.f * acc[rg][cg][i][1];
                o.z = xs + cs.z - 2.f * acc[rg][cg][i][2];
                o.w = xs + cs.w - 2.f * acc[rg][cg][i][3];
                *reinterpret_cast<float4*>(Dist + (size_t)row * K_ + col) = o;
            }
        }
}

// ---------------- fused: softmax + argmin + quantize + ql + probs ----------------
__global__ __launch_bounds__(256) void softmax_quant(
        float* __restrict__ Dist, const float* __restrict__ X,
        const float* __restrict__ C, float* __restrict__ outq,
        float* __restrict__ probs, double* __restrict__ ql_acc) {
    int row = blockIdx.x;
    int t = threadIdx.x;
    int wave = t >> 6, lane = t & 63;
    float* drow = Dist + (size_t)row * K_;

    float v[8];
    float4 v0 = *reinterpret_cast<const float4*>(drow + t * 8);
    float4 v1 = *reinterpret_cast<const float4*>(drow + t * 8 + 4);
    v[0]=v0.x; v[1]=v0.y; v[2]=v0.z; v[3]=v0.w;
    v[4]=v1.x; v[5]=v1.y; v[6]=v1.z; v[7]=v1.w;

    // per-thread min, first-index tiebreak (chunk contiguous -> strict <)
    float bv = v[0]; int bi = t * 8;
    #pragma unroll
    for (int j = 1; j < 8; ++j) if (v[j] < bv) { bv = v[j]; bi = t * 8 + j; }
    // wave butterfly min with index tiebreak
    #pragma unroll
    for (int off = 32; off > 0; off >>= 1) {
        float ov = __shfl_xor(bv, off, 64);
        int   oi = __shfl_xor(bi, off, 64);
        if (ov < bv || (ov == bv && oi < bi)) { bv = ov; bi = oi; }
    }
    __shared__ float wv[4]; __shared__ int wi[4]; __shared__ float ws[4];
    if (lane == 0) { wv[wave] = bv; wi[wave] = bi; }
    __syncthreads();
    float dmin = wv[0]; int amin = wi[0];
    #pragma unroll
    for (int w = 1; w < 4; ++w) {
        if (wv[w] < dmin || (wv[w] == dmin && wi[w] < amin)) { dmin = wv[w]; amin = wi[w]; }
    }

    // exp and sum
    float e[8]; float s = 0.f;
    #pragma unroll
    for (int j = 0; j < 8; ++j) { e[j] = __expf(-100.f * (v[j] - dmin)) ; s += e[j]; }
    s = waveReduceSum(s);
    if (lane == 0) ws[wave] = s;
    __syncthreads();
    float inv = 1.f / (ws[0] + ws[1] + ws[2] + ws[3]);

    float4 o0 = make_float4(e[0]*inv, e[1]*inv, e[2]*inv, e[3]*inv);
    float4 o1 = make_float4(e[4]*inv, e[5]*inv, e[6]*inv, e[7]*inv);
    *reinterpret_cast<float4*>(drow + t * 8)     = o0;
    *reinterpret_cast<float4*>(drow + t * 8 + 4) = o1;

    // quantize (wave 0): outq[row] = C[amin], ql += ||x - q||^2
    if (wave == 0) {
        float4 q = *reinterpret_cast<const float4*>(C + (size_t)amin * D_ + lane * 4);
        float4 x = *reinterpret_cast<const float4*>(X + (size_t)row * D_ + lane * 4);
        *reinterpret_cast<float4*>(outq + (size_t)row * D_ + lane * 4) = q;
        float dx = x.x-q.x, dy = x.y-q.y, dz = x.z-q.z, dw = x.w-q.w;
        float sq = dx*dx + dy*dy + dz*dz + dw*dw;
        sq = waveReduceSum(sq);
        if (lane == 0) {
            atomicAdd(ql_acc, (double)sq);
            probs[row] = 1.0f / (float)K_;
        }
    }
}

// ---------------- finalize scalars ----------------
__global__ void finalize_kernel(const double* __restrict__ acc, float* __restrict__ o) {
    // acc: 0 xsq_total, 1 sa_sq_total, 2 w_total, 3 use_sum, 4 ql_sum
    o[0] = (float)(acc[4] / (double)R_);
    o[1] = (float)(acc[3] / (double)K_);
    o[2] = (float)(2.0 * acc[0] / (double)R_
                 - 2.0 * acc[1] / ((double)B_ * (double)B_ * (double)A_));
}

extern "C" void kernel_launch(void* const* d_in, const int* in_sizes, int n_in,
                              void* d_out, int out_size, void* d_ws, size_t ws_size,
                              hipStream_t stream) {
    const float* X  = (const float*)d_in[0];
    const float* C  = (const float*)d_in[1];
    const float* W  = (const float*)d_in[2];
    const int*   RI = (const int*)d_in[3];

    float* out    = (float*)d_out;
    float* out_q  = out;
    float* out_p  = out_q + (size_t)R_ * D_;
    float* out_s  = out_p + R_;                  // (R_, K_) soft_one_hot / dist scratch
    float* out_sc = out_s + (size_t)R_ * K_;

    double* acc = (double*)d_ws;
    float*  xsq = (float*)((char*)d_ws + 64);
    float*  csq = xsq + R_;

    hipMemsetAsync(d_ws, 0, 64, stream);

    hipLaunchKernelGGL(row_sqnorm, dim3(R_/4), dim3(256), 0, stream, X, xsq, acc + 0, R_);
    hipLaunchKernelGGL(row_sqnorm, dim3(K_/4), dim3(256), 0, stream, C, csq, (double*)nullptr, K_);
    hipLaunchKernelGGL(col_sum_sq, dim3((A_*D_)/256), dim3(256), 0, stream, X, acc + 1);
    hipLaunchKernelGGL(wsum_kernel, dim3(1), dim3(256), 0, stream, W, acc);
    hipLaunchKernelGGL(useless_kernel, dim3(K_/4), dim3(256), 0, stream, X, C, W, RI, acc, acc + 3);
    hipLaunchKernelGGL(dist_gemm, dim3(K_/BN, R_/BM), dim3(256), 0, stream, X, C, xsq, csq, out_s);
    hipLaunchKernelGGL(softmax_quant, dim3(R_), dim3(256), 0, stream, out_s, X, C, out_q, out_p, acc + 4);
    hipLaunchKernelGGL(finalize_kernel, dim3(1), dim3(1), 0, stream, acc, out_sc);
}

// Round 4
// 271.477 us; speedup vs baseline: 1.5498x; 1.3898x over previous
//
#include <hip/hip_runtime.h>

#define B_ 128
#define A_ 64
#define D_ 256
#define K_ 2048
#define R_ (B_*A_)   // 8192
#define KEFF 512     // [hi|lo] split doubles K
#define NST 16       // KEFF / 32 stages

typedef __attribute__((ext_vector_type(8))) short bf16x8;
typedef __attribute__((ext_vector_type(4))) float f32x4;

// ---------------- utility ----------------
__device__ inline float waveReduceSum(float v) {   // butterfly: all lanes get total
    #pragma unroll
    for (int off = 32; off > 0; off >>= 1)
        v += __shfl_xor(v, off, 64);
    return v;
}
__device__ inline unsigned short f2bf(float f) {   // RNE
    unsigned int u = __float_as_uint(f);
    return (unsigned short)((u + 0x7fffu + ((u >> 16) & 1u)) >> 16);
}
__device__ inline float bf2f(unsigned short h) {
    return __uint_as_float((unsigned int)h << 16);
}
__device__ inline bool ltidx(float a, int ia, float b, int ib) {
    return a < b || (a == b && ia < ib);
}

// ---------------- convert X -> staged bf16 hi/lo + xsq + total ----------------
// XPs layout: [rb(64)][t(16)][chunk c(512)=kc*128+row][8 shorts]
// hi -> t=korig>>5, lo -> t=8+(korig>>5); kc=(korig>>3)&3, j=korig&7.
__global__ void convertX(const float* __restrict__ X, short* __restrict__ XPs,
                         float* __restrict__ xsq, double* __restrict__ tot) {
    int wave = threadIdx.x >> 6, lane = threadIdx.x & 63;
    int row = blockIdx.x * 4 + wave;
    int korig = lane * 4;
    float4 v = *reinterpret_cast<const float4*>(X + (size_t)row * D_ + korig);
    float f[4] = {v.x, v.y, v.z, v.w};
    ushort4 hi, lo;
    unsigned short* hp = (unsigned short*)&hi;
    unsigned short* lp = (unsigned short*)&lo;
    float s = 0.f;
    #pragma unroll
    for (int q = 0; q < 4; ++q) {
        s += f[q] * f[q];
        unsigned short h = f2bf(f[q]);
        hp[q] = h;
        lp[q] = f2bf(f[q] - bf2f(h));
    }
    int rb = row >> 7, r = row & 127;
    int t = korig >> 5, kc = (korig >> 3) & 3, j = korig & 7;
    size_t base = ((size_t)rb * 16) * 4096 + (size_t)kc * 1024 + (size_t)r * 8 + j;
    *reinterpret_cast<ushort4*>(XPs + base + (size_t)t * 4096)       = hi;
    *reinterpret_cast<ushort4*>(XPs + base + (size_t)(t + 8) * 4096) = lo;
    s = waveReduceSum(s);
    if (lane == 0) {
        xsq[row] = s;
        atomicAdd(tot, (double)s);
    }
}

// ---------------- convert C -> CP1s=[ch tiles 0-7 | cl tiles 8-15] + csq ----------------
__global__ void convertC(const float* __restrict__ C, short* __restrict__ CP1s,
                         float* __restrict__ csq) {
    int wave = threadIdx.x >> 6, lane = threadIdx.x & 63;
    int row = blockIdx.x * 4 + wave;
    int korig = lane * 4;
    float4 v = *reinterpret_cast<const float4*>(C + (size_t)row * D_ + korig);
    float f[4] = {v.x, v.y, v.z, v.w};
    ushort4 hi, lo;
    unsigned short* hp = (unsigned short*)&hi;
    unsigned short* lp = (unsigned short*)&lo;
    float s = 0.f;
    #pragma unroll
    for (int q = 0; q < 4; ++q) {
        s += f[q] * f[q];
        unsigned short h = f2bf(f[q]);
        hp[q] = h;
        lp[q] = f2bf(f[q] - bf2f(h));
    }
    int rb = row >> 7, r = row & 127;
    int t = korig >> 5, kc = (korig >> 3) & 3, j = korig & 7;
    size_t base = ((size_t)rb * 16) * 4096 + (size_t)kc * 1024 + (size_t)r * 8 + j;
    *reinterpret_cast<ushort4*>(CP1s + base + (size_t)t * 4096)       = hi;
    *reinterpret_cast<ushort4*>(CP1s + base + (size_t)(t + 8) * 4096) = lo;
    s = waveReduceSum(s);
    if (lane == 0) csq[row] = s;
}

// ---------------- row squared norms (fallback path) ----------------
__global__ void row_sqnorm(const float* __restrict__ X, float* __restrict__ out,
                           double* __restrict__ tot, int rows) {
    int wave = threadIdx.x >> 6, lane = threadIdx.x & 63;
    int row  = blockIdx.x * 4 + wave;
    if (row >= rows) return;
    float4 v = *reinterpret_cast<const float4*>(X + (size_t)row * D_ + lane * 4);
    float s = v.x*v.x + v.y*v.y + v.z*v.z + v.w*v.w;
    s = waveReduceSum(s);
    if (lane == 0) {
        out[row] = s;
        if (tot) atomicAdd(tot, (double)s);
    }
}

// ---------------- latent diversity: sum_a ||sum_i x[i,a,:]||^2 ----------------
__global__ void col_sum_sq(const float* __restrict__ X, double* __restrict__ acc) {
    int idx = blockIdx.x * blockDim.x + threadIdx.x;
    float s = 0.f;
    #pragma unroll 4
    for (int i = 0; i < B_; ++i) s += X[(size_t)i * (A_*D_) + idx];
    float p = s * s;
    p = waveReduceSum(p);
    __shared__ float red[4];
    int wave = threadIdx.x >> 6, lane = threadIdx.x & 63;
    if (lane == 0) red[wave] = p;
    __syncthreads();
    if (threadIdx.x == 0)
        atomicAdd(acc, (double)(red[0] + red[1] + red[2] + red[3]));
}

// ---------------- weights total ----------------
__global__ void wsum_kernel(const float* __restrict__ w, double* __restrict__ acc) {
    double s = 0.0;
    for (int i = threadIdx.x; i < K_; i += 256) s += (double)w[i];
    __shared__ double red[256];
    red[threadIdx.x] = s; __syncthreads();
    for (int off = 128; off > 0; off >>= 1) {
        if (threadIdx.x < off) red[threadIdx.x] += red[threadIdx.x + off];
        __syncthreads();
    }
    if (threadIdx.x == 0) acc[2] = red[0];
}

// ---------------- uselessness ----------------
__global__ void useless_kernel(const float* __restrict__ X, const float* __restrict__ C,
                               const float* __restrict__ w, const int* __restrict__ ridx,
                               const double* __restrict__ acc_in, double* __restrict__ use_acc) {
    int wave = threadIdx.x >> 6, lane = threadIdx.x & 63;
    int k = blockIdx.x * 4 + wave;
    if (k >= K_) return;
    float cutoff = (float)(acc_in[2] / (100.0 * (double)K_));
    if (!(w[k] < cutoff)) return;
    int r = ridx[k];
    float4 xv = *reinterpret_cast<const float4*>(X + (size_t)r * D_ + lane * 4);
    float4 cv = *reinterpret_cast<const float4*>(C + (size_t)k * D_ + lane * 4);
    float s = logf(fabsf(xv.x - cv.x) + 1.f) + logf(fabsf(xv.y - cv.y) + 1.f)
            + logf(fabsf(xv.z - cv.z) + 1.f) + logf(fabsf(xv.w - cv.w) + 1.f);
    s = waveReduceSum(s);
    if (lane == 0) atomicAdd(use_acc, (double)s);
}

// ---------------- MFMA distance GEMM (split-bf16) ----------------
// 128x128 tile, 4 waves (2x2), each wave 64x64 = 4x4 MFMA 16x16x32 tiles.
// B2 tile t == CP1s tile t^8 (hi<->lo swap), so only one staged C array.
__global__ __launch_bounds__(256, 3) void dist_mfma(
        const short* __restrict__ XPs, const short* __restrict__ CP1s,
        const float* __restrict__ xsq, const float* __restrict__ csq,
        float* __restrict__ Dist) {
    __shared__ short lds[2][3 * 4096];
    int tid = threadIdx.x;
    int lane = tid & 63, wid = tid >> 6;
    int wrow = wid >> 1, wcol = wid & 1;
    int bm0 = blockIdx.y * 128, bn0 = blockIdx.x * 128;

    f32x4 acc[4][4] = {};

    auto STAGE = [&](int buf, int t) {
        #pragma unroll
        for (int is = 0; is < 6; ++is) {
            int c = is * 256 + tid;           // 0..1535
            int tile = c >> 9, cc = c & 511;
            const short* gsrc;
            if (tile == 0)      gsrc = XPs  + (((size_t)blockIdx.y * 16 + t) * 512 + cc) * 8;
            else if (tile == 1) gsrc = CP1s + (((size_t)blockIdx.x * 16 + t) * 512 + cc) * 8;
            else                gsrc = CP1s + (((size_t)blockIdx.x * 16 + (t ^ 8)) * 512 + cc) * 8;
            short* ldst = &lds[buf][(is * 256 + wid * 64) * 8];  // wave-uniform base
            __builtin_amdgcn_global_load_lds(
                (const __attribute__((address_space(1))) unsigned int*)gsrc,
                (__attribute__((address_space(3))) unsigned int*)ldst,
                16, 0, 0);
        }
    };

    STAGE(0, 0);
    __syncthreads();

    int kc = lane >> 4;       // k-chunk 0..3
    int lr = lane & 15;

    for (int t = 0; t < NST; ++t) {
        if (t + 1 < NST) STAGE((t + 1) & 1, t + 1);
        const short* At  = &lds[t & 1][0];
        const short* B1t = &lds[t & 1][4096];
        const short* B2t = &lds[t & 1][8192];
        bf16x8 af[4], b1f[4], b2f[4];
        #pragma unroll
        for (int i = 0; i < 4; ++i) {
            af[i]  = *(const bf16x8*)(At  + ((size_t)kc * 128 + wrow * 64 + i * 16 + lr) * 8);
            b1f[i] = *(const bf16x8*)(B1t + ((size_t)kc * 128 + wcol * 64 + i * 16 + lr) * 8);
            b2f[i] = *(const bf16x8*)(B2t + ((size_t)kc * 128 + wcol * 64 + i * 16 + lr) * 8);
        }
        #pragma unroll
        for (int i = 0; i < 4; ++i)
            #pragma unroll
            for (int j = 0; j < 4; ++j) {
                acc[i][j] = __builtin_amdgcn_mfma_f32_16x16x32_bf16(af[i], b1f[j], acc[i][j], 0, 0, 0);
                acc[i][j] = __builtin_amdgcn_mfma_f32_16x16x32_bf16(af[i], b2f[j], acc[i][j], 0, 0, 0);
            }
        __syncthreads();
    }

    // C/D layout: col = lane&15, row = (lane>>4)*4 + reg
    #pragma unroll
    for (int i = 0; i < 4; ++i) {
        int row0 = bm0 + wrow * 64 + i * 16 + (lane >> 4) * 4;
        #pragma unroll
        for (int j = 0; j < 4; ++j) {
            int col = bn0 + wcol * 64 + j * 16 + (lane & 15);
            float cs = csq[col];
            #pragma unroll
            for (int r = 0; r < 4; ++r) {
                float xs = xsq[row0 + r];
                Dist[(size_t)(row0 + r) * K_ + col] = xs + cs - 2.f * acc[i][j][r];
            }
        }
    }
}

// ---------------- fp32 fallback distance GEMM (proven R2 kernel) ----------------
#define BM 128
#define BN 128
#define BK 16
__global__ __launch_bounds__(256, 4) void dist_gemm(
        const float* __restrict__ X, const float* __restrict__ C,
        const float* __restrict__ xsq, const float* __restrict__ csq,
        float* __restrict__ Dist) {
    __shared__ float As[BK][BM + 4];
    __shared__ float Bs[BK][BN + 4];
    int tid = threadIdx.x;
    int tx = tid & 15, ty = tid >> 4;
    int bm0 = blockIdx.y * BM, bn0 = blockIdx.x * BN;
    int r = tid & 127;
    const float* src = (tid < 128) ? (X + (size_t)(bm0 + r) * D_)
                                   : (C + (size_t)(bn0 + r) * D_);
    float* dst = (tid < 128) ? &As[0][0] : &Bs[0][0];
    float acc[2][2][4][4] = {};
    float4 p0 = *reinterpret_cast<const float4*>(src + 0);
    float4 p1 = *reinterpret_cast<const float4*>(src + 4);
    float4 p2 = *reinterpret_cast<const float4*>(src + 8);
    float4 p3 = *reinterpret_cast<const float4*>(src + 12);
    for (int t = 0; t < D_ / BK; ++t) {
        __syncthreads();
        dst[ 0*(BM+4) + r] = p0.x; dst[ 1*(BM+4) + r] = p0.y;
        dst[ 2*(BM+4) + r] = p0.z; dst[ 3*(BM+4) + r] = p0.w;
        dst[ 4*(BM+4) + r] = p1.x; dst[ 5*(BM+4) + r] = p1.y;
        dst[ 6*(BM+4) + r] = p1.z; dst[ 7*(BM+4) + r] = p1.w;
        dst[ 8*(BM+4) + r] = p2.x; dst[ 9*(BM+4) + r] = p2.y;
        dst[10*(BM+4) + r] = p2.z; dst[11*(BM+4) + r] = p2.w;
        dst[12*(BM+4) + r] = p3.x; dst[13*(BM+4) + r] = p3.y;
        dst[14*(BM+4) + r] = p3.z; dst[15*(BM+4) + r] = p3.w;
        __syncthreads();
        if (t < D_ / BK - 1) {
            const float* s2 = src + (t + 1) * BK;
            p0 = *reinterpret_cast<const float4*>(s2 + 0);
            p1 = *reinterpret_cast<const float4*>(s2 + 4);
            p2 = *reinterpret_cast<const float4*>(s2 + 8);
            p3 = *reinterpret_cast<const float4*>(s2 + 12);
        }
        #pragma unroll
        for (int kk = 0; kk < BK; ++kk) {
            float4 a0 = *reinterpret_cast<const float4*>(&As[kk][ty * 4]);
            float4 a1 = *reinterpret_cast<const float4*>(&As[kk][64 + ty * 4]);
            float4 b0 = *reinterpret_cast<const float4*>(&Bs[kk][tx * 4]);
            float4 b1 = *reinterpret_cast<const float4*>(&Bs[kk][64 + tx * 4]);
            float af[2][4] = {{a0.x, a0.y, a0.z, a0.w}, {a1.x, a1.y, a1.z, a1.w}};
            float bf[2][4] = {{b0.x, b0.y, b0.z, b0.w}, {b1.x, b1.y, b1.z, b1.w}};
            #pragma unroll
            for (int rg = 0; rg < 2; ++rg)
                #pragma unroll
                for (int cg = 0; cg < 2; ++cg)
                    #pragma unroll
                    for (int i = 0; i < 4; ++i)
                        #pragma unroll
                        for (int j = 0; j < 4; ++j)
                            acc[rg][cg][i][j] += af[rg][i] * bf[cg][j];
        }
    }
    #pragma unroll
    for (int rg = 0; rg < 2; ++rg)
        #pragma unroll
        for (int i = 0; i < 4; ++i) {
            int row = bm0 + rg * 64 + ty * 4 + i;
            float xs = xsq[row];
            #pragma unroll
            for (int cg = 0; cg < 2; ++cg) {
                int col = bn0 + cg * 64 + tx * 4;
                float4 cs = *reinterpret_cast<const float4*>(csq + col);
                float4 o;
                o.x = xs + cs.x - 2.f * acc[rg][cg][i][0];
                o.y = xs + cs.y - 2.f * acc[rg][cg][i][1];
                o.z = xs + cs.z - 2.f * acc[rg][cg][i][2];
                o.w = xs + cs.w - 2.f * acc[rg][cg][i][3];
                *reinterpret_cast<float4*>(Dist + (size_t)row * K_ + col) = o;
            }
        }
}

// ---------------- fused: softmax + top-2 argmin + exact refine + quantize ----------------
__global__ __launch_bounds__(256) void softmax_quant(
        float* __restrict__ Dist, const float* __restrict__ X,
        const float* __restrict__ C, float* __restrict__ outq,
        float* __restrict__ probs, double* __restrict__ ql_acc) {
    int row = blockIdx.x;
    int t = threadIdx.x;
    int wave = t >> 6, lane = t & 63;
    float* drow = Dist + (size_t)row * K_;

    float v[8];
    float4 v0 = *reinterpret_cast<const float4*>(drow + t * 8);
    float4 v1v = *reinterpret_cast<const float4*>(drow + t * 8 + 4);
    v[0]=v0.x; v[1]=v0.y; v[2]=v0.z; v[3]=v0.w;
    v[4]=v1v.x; v[5]=v1v.y; v[6]=v1v.z; v[7]=v1v.w;

    // per-thread top-2 (ascending index -> first-index tiebreak)
    float v1 = v[0]; int i1 = t * 8;
    float v2 = 3.4e38f; int i2 = 0x7fffffff;
    #pragma unroll
    for (int j = 1; j < 8; ++j) {
        int idx = t * 8 + j;
        if (v[j] < v1) { v2 = v1; i2 = i1; v1 = v[j]; i1 = idx; }
        else if (ltidx(v[j], idx, v2, i2)) { v2 = v[j]; i2 = idx; }
    }
    // wave butterfly top-2 merge
    #pragma unroll
    for (int off = 32; off > 0; off >>= 1) {
        float w1 = __shfl_xor(v1, off, 64); int j1 = __shfl_xor(i1, off, 64);
        float w2 = __shfl_xor(v2, off, 64); int j2 = __shfl_xor(i2, off, 64);
        if (ltidx(w1, j1, v1, i1)) {
            if (ltidx(v1, i1, w2, j2)) { v2 = v1; i2 = i1; }
            else                       { v2 = w2; i2 = j2; }
            v1 = w1; i1 = j1;
        } else if (ltidx(w1, j1, v2, i2)) { v2 = w1; i2 = j1; }
    }
    __shared__ float sv1[4], sv2[4]; __shared__ int si1[4], si2[4];
    __shared__ float ws[4];
    if (lane == 0) { sv1[wave] = v1; si1[wave] = i1; sv2[wave] = v2; si2[wave] = i2; }
    __syncthreads();
    float dmin = sv1[0]; int am = si1[0];
    float d2nd = sv2[0]; int am2 = si2[0];
    #pragma unroll
    for (int w = 1; w < 4; ++w) {
        float w1 = sv1[w]; int j1 = si1[w];
        float w2 = sv2[w]; int j2 = si2[w];
        if (ltidx(w1, j1, dmin, am)) {
            if (ltidx(dmin, am, w2, j2)) { d2nd = dmin; am2 = am; }
            else                         { d2nd = w2;   am2 = j2; }
            dmin = w1; am = j1;
        } else if (ltidx(w1, j1, d2nd, am2)) { d2nd = w1; am2 = j1; }
    }

    // softmax (shift by dmin; any constant shift cancels exactly)
    float e[8]; float s = 0.f;
    #pragma unroll
    for (int j = 0; j < 8; ++j) { e[j] = __expf(-100.f * (v[j] - dmin)); s += e[j]; }
    s = waveReduceSum(s);
    if (lane == 0) ws[wave] = s;
    __syncthreads();
    float inv = 1.f / (ws[0] + ws[1] + ws[2] + ws[3]);

    float4 o0 = make_float4(e[0]*inv, e[1]*inv, e[2]*inv, e[3]*inv);
    float4 o1 = make_float4(e[4]*inv, e[5]*inv, e[6]*inv, e[7]*inv);
    *reinterpret_cast<float4*>(drow + t * 8)     = o0;
    *reinterpret_cast<float4*>(drow + t * 8 + 4) = o1;

    // exact fp32 refinement of top-2 + quantize + ql (wave 0)
    if (wave == 0) {
        float4 x  = *reinterpret_cast<const float4*>(X + (size_t)row * D_ + lane * 4);
        float4 c1 = *reinterpret_cast<const float4*>(C + (size_t)am  * D_ + lane * 4);
        float4 c2 = *reinterpret_cast<const float4*>(C + (size_t)am2 * D_ + lane * 4);
        float d1x = (x.x-c1.x)*(x.x-c1.x) + (x.y-c1.y)*(x.y-c1.y)
                  + (x.z-c1.z)*(x.z-c1.z) + (x.w-c1.w)*(x.w-c1.w);
        float d2x = (x.x-c2.x)*(x.x-c2.x) + (x.y-c2.y)*(x.y-c2.y)
                  + (x.z-c2.z)*(x.z-c2.z) + (x.w-c2.w)*(x.w-c2.w);
        d1x = waveReduceSum(d1x);   // all lanes get totals (butterfly)
        d2x = waveReduceSum(d2x);
        bool pick2 = ltidx(d2x, am2, d1x, am);
        float4 q = pick2 ? c2 : c1;
        float dq = pick2 ? d2x : d1x;
        *reinterpret_cast<float4*>(outq + (size_t)row * D_ + lane * 4) = q;
        if (lane == 0) {
            atomicAdd(ql_acc, (double)dq);
            probs[row] = 1.0f / (float)K_;
        }
    }
}

// ---------------- finalize scalars ----------------
__global__ void finalize_kernel(const double* __restrict__ acc, float* __restrict__ o) {
    o[0] = (float)(acc[4] / (double)R_);
    o[1] = (float)(acc[3] / (double)K_);
    o[2] = (float)(2.0 * acc[0] / (double)R_
                 - 2.0 * acc[1] / ((double)B_ * (double)B_ * (double)A_));
}

extern "C" void kernel_launch(void* const* d_in, const int* in_sizes, int n_in,
                              void* d_out, int out_size, void* d_ws, size_t ws_size,
                              hipStream_t stream) {
    const float* X  = (const float*)d_in[0];
    const float* C  = (const float*)d_in[1];
    const float* W  = (const float*)d_in[2];
    const int*   RI = (const int*)d_in[3];

    float* out    = (float*)d_out;
    float* out_q  = out;                         // R_*D_ floats (8 MB)
    float* out_p  = out_q + (size_t)R_ * D_;     // R_
    float* out_s  = out_p + R_;                  // R_*K_ (dist scratch -> soft_one_hot)
    float* out_sc = out_s + (size_t)R_ * K_;     // 3 scalars

    char* wsb = (char*)d_ws;
    double* acc  = (double*)wsb;                          // 5 doubles
    float*  xsq  = (float*)(wsb + 64);                    // R_ floats (32 KB)
    float*  csq  = (float*)(wsb + 64 + R_ * 4);           // K_ floats (8 KB)
    short*  CP1s = (short*)(wsb + 64 + R_ * 4 + K_ * 4);  // K_*KEFF shorts (2 MB)

    const size_t WS_NEEDED = 64 + (size_t)R_*4 + (size_t)K_*4 + (size_t)K_*KEFF*2;

    hipMemsetAsync(d_ws, 0, 64, stream);

    hipLaunchKernelGGL(col_sum_sq, dim3((A_*D_)/256), dim3(256), 0, stream, X, acc + 1);
    hipLaunchKernelGGL(wsum_kernel, dim3(1), dim3(256), 0, stream, W, acc);
    hipLaunchKernelGGL(useless_kernel, dim3(K_/4), dim3(256), 0, stream, X, C, W, RI, acc, acc + 3);

    if (ws_size >= WS_NEEDED) {
        // MFMA split-bf16 path; XPs staged in out_q region (consumed before overwrite)
        short* XPs = (short*)out_q;   // R_*KEFF shorts == R_*D_ floats == 8 MB exact
        hipLaunchKernelGGL(convertX, dim3(R_/4), dim3(256), 0, stream, X, XPs, xsq, acc + 0);
        hipLaunchKernelGGL(convertC, dim3(K_/4), dim3(256), 0, stream, C, CP1s, csq);
        hipLaunchKernelGGL(dist_mfma, dim3(K_/128, R_/128), dim3(256), 0, stream,
                           XPs, CP1s, xsq, csq, out_s);
    } else {
        // fp32 fallback (41 KB ws, proven)
        hipLaunchKernelGGL(row_sqnorm, dim3(R_/4), dim3(256), 0, stream, X, xsq, acc + 0, R_);
        hipLaunchKernelGGL(row_sqnorm, dim3(K_/4), dim3(256), 0, stream, C, csq, (double*)nullptr, K_);
        hipLaunchKernelGGL(dist_gemm, dim3(K_/BN, R_/BM), dim3(256), 0, stream, X, C, xsq, csq, out_s);
    }

    hipLaunchKernelGGL(softmax_quant, dim3(R_), dim3(256), 0, stream, out_s, X, C, out_q, out_p, acc + 4);
    hipLaunchKernelGGL(finalize_kernel, dim3(1), dim3(1), 0, stream, acc, out_sc);
}

// Round 5
// 101.879 us; speedup vs baseline: 4.1297x; 2.6647x over previous
//
#include <hip/hip_runtime.h>

#define B_ 128
#define A_ 64
#define D_ 256
#define K_ 2048
#define R_ (B_*A_)   // 8192
#define KEFF 512     // [hi|lo] split doubles K
#define NST 16       // KEFF / 32 stages

typedef __attribute__((ext_vector_type(8))) short bf16x8;
typedef __attribute__((ext_vector_type(4))) float f32x4;

// ---------------- utility ----------------
__device__ inline float waveReduceSum(float v) {   // butterfly: all lanes get total
    #pragma unroll
    for (int off = 32; off > 0; off >>= 1)
        v += __shfl_xor(v, off, 64);
    return v;
}
__device__ inline unsigned short f2bf(float f) {   // RNE
    unsigned int u = __float_as_uint(f);
    return (unsigned short)((u + 0x7fffu + ((u >> 16) & 1u)) >> 16);
}
__device__ inline float bf2f(unsigned short h) {
    return __uint_as_float((unsigned int)h << 16);
}
__device__ inline bool ltidx(float a, int ia, float b, int ib) {
    return a < b || (a == b && ia < ib);
}

// ---------------- convert X -> staged bf16 hi/lo + xsq ----------------
// XPs layout: [rb(64)][t(16)][chunk c(512)=kc*128+row][8 shorts]
// hi -> t=korig>>5, lo -> t=8+(korig>>5); kc=(korig>>3)&3, j=korig&7.
__global__ void convertX(const float* __restrict__ X, short* __restrict__ XPs,
                         float* __restrict__ xsq) {
    int wave = threadIdx.x >> 6, lane = threadIdx.x & 63;
    int row = blockIdx.x * 4 + wave;
    int korig = lane * 4;
    float4 v = *reinterpret_cast<const float4*>(X + (size_t)row * D_ + korig);
    float f[4] = {v.x, v.y, v.z, v.w};
    ushort4 hi, lo;
    unsigned short* hp = (unsigned short*)&hi;
    unsigned short* lp = (unsigned short*)&lo;
    float s = 0.f;
    #pragma unroll
    for (int q = 0; q < 4; ++q) {
        s += f[q] * f[q];
        unsigned short h = f2bf(f[q]);
        hp[q] = h;
        lp[q] = f2bf(f[q] - bf2f(h));
    }
    int rb = row >> 7, r = row & 127;
    int t = korig >> 5, kc = (korig >> 3) & 3, j = korig & 7;
    size_t base = ((size_t)rb * 16) * 4096 + (size_t)kc * 1024 + (size_t)r * 8 + j;
    *reinterpret_cast<ushort4*>(XPs + base + (size_t)t * 4096)       = hi;
    *reinterpret_cast<ushort4*>(XPs + base + (size_t)(t + 8) * 4096) = lo;
    s = waveReduceSum(s);
    if (lane == 0) xsq[row] = s;
}

// ---------------- convert C -> CP1s=[ch tiles 0-7 | cl tiles 8-15] + csq ----------------
__global__ void convertC(const float* __restrict__ C, short* __restrict__ CP1s,
                         float* __restrict__ csq) {
    int wave = threadIdx.x >> 6, lane = threadIdx.x & 63;
    int row = blockIdx.x * 4 + wave;
    int korig = lane * 4;
    float4 v = *reinterpret_cast<const float4*>(C + (size_t)row * D_ + korig);
    float f[4] = {v.x, v.y, v.z, v.w};
    ushort4 hi, lo;
    unsigned short* hp = (unsigned short*)&hi;
    unsigned short* lp = (unsigned short*)&lo;
    float s = 0.f;
    #pragma unroll
    for (int q = 0; q < 4; ++q) {
        s += f[q] * f[q];
        unsigned short h = f2bf(f[q]);
        hp[q] = h;
        lp[q] = f2bf(f[q] - bf2f(h));
    }
    int rb = row >> 7, r = row & 127;
    int t = korig >> 5, kc = (korig >> 3) & 3, j = korig & 7;
    size_t base = ((size_t)rb * 16) * 4096 + (size_t)kc * 1024 + (size_t)r * 8 + j;
    *reinterpret_cast<ushort4*>(CP1s + base + (size_t)t * 4096)       = hi;
    *reinterpret_cast<ushort4*>(CP1s + base + (size_t)(t + 8) * 4096) = lo;
    s = waveReduceSum(s);
    if (lane == 0) csq[row] = s;
}

// ---------------- row squared norms (fallback path) ----------------
__global__ void row_sqnorm(const float* __restrict__ X, float* __restrict__ out, int rows) {
    int wave = threadIdx.x >> 6, lane = threadIdx.x & 63;
    int row  = blockIdx.x * 4 + wave;
    if (row >= rows) return;
    float4 v = *reinterpret_cast<const float4*>(X + (size_t)row * D_ + lane * 4);
    float s = v.x*v.x + v.y*v.y + v.z*v.z + v.w*v.w;
    s = waveReduceSum(s);
    if (lane == 0) out[row] = s;
}

// ---------------- latent diversity partials: per-block sum_a ||sum_i x[i,a,:]||^2 ----------------
__global__ void col_sum_sq(const float* __restrict__ X, float* __restrict__ part) {
    int idx = blockIdx.x * blockDim.x + threadIdx.x;
    float s = 0.f;
    #pragma unroll 4
    for (int i = 0; i < B_; ++i) s += X[(size_t)i * (A_*D_) + idx];
    float p = s * s;
    p = waveReduceSum(p);
    __shared__ float red[4];
    int wave = threadIdx.x >> 6, lane = threadIdx.x & 63;
    if (lane == 0) red[wave] = p;
    __syncthreads();
    if (threadIdx.x == 0) part[blockIdx.x] = red[0] + red[1] + red[2] + red[3];
}

// ---------------- weights total ----------------
__global__ void wsum_kernel(const float* __restrict__ w, double* __restrict__ acc) {
    double s = 0.0;
    for (int i = threadIdx.x; i < K_; i += 256) s += (double)w[i];
    __shared__ double red[256];
    red[threadIdx.x] = s; __syncthreads();
    for (int off = 128; off > 0; off >>= 1) {
        if (threadIdx.x < off) red[threadIdx.x] += red[threadIdx.x + off];
        __syncthreads();
    }
    if (threadIdx.x == 0) acc[2] = red[0];
}

// ---------------- uselessness (few active waves -> atomics fine) ----------------
__global__ void useless_kernel(const float* __restrict__ X, const float* __restrict__ C,
                               const float* __restrict__ w, const int* __restrict__ ridx,
                               const double* __restrict__ acc_in, double* __restrict__ use_acc) {
    int wave = threadIdx.x >> 6, lane = threadIdx.x & 63;
    int k = blockIdx.x * 4 + wave;
    if (k >= K_) return;
    float cutoff = (float)(acc_in[2] / (100.0 * (double)K_));
    if (!(w[k] < cutoff)) return;
    int r = ridx[k];
    float4 xv = *reinterpret_cast<const float4*>(X + (size_t)r * D_ + lane * 4);
    float4 cv = *reinterpret_cast<const float4*>(C + (size_t)k * D_ + lane * 4);
    float s = logf(fabsf(xv.x - cv.x) + 1.f) + logf(fabsf(xv.y - cv.y) + 1.f)
            + logf(fabsf(xv.z - cv.z) + 1.f) + logf(fabsf(xv.w - cv.w) + 1.f);
    s = waveReduceSum(s);
    if (lane == 0) atomicAdd(use_acc, (double)s);
}

// ---------------- MFMA distance GEMM (split-bf16) ----------------
// 128x128 tile, 4 waves (2x2), each wave 64x64 = 4x4 MFMA 16x16x32 tiles.
// B2 tile t == CP1s tile t^8 (hi<->lo swap), so only one staged C array.
__global__ __launch_bounds__(256, 3) void dist_mfma(
        const short* __restrict__ XPs, const short* __restrict__ CP1s,
        const float* __restrict__ xsq, const float* __restrict__ csq,
        float* __restrict__ Dist) {
    __shared__ short lds[2][3 * 4096];
    int tid = threadIdx.x;
    int lane = tid & 63, wid = tid >> 6;
    int wrow = wid >> 1, wcol = wid & 1;
    int bm0 = blockIdx.y * 128, bn0 = blockIdx.x * 128;

    f32x4 acc[4][4] = {};

    auto STAGE = [&](int buf, int t) {
        #pragma unroll
        for (int is = 0; is < 6; ++is) {
            int c = is * 256 + tid;           // 0..1535
            int tile = c >> 9, cc = c & 511;
            const short* gsrc;
            if (tile == 0)      gsrc = XPs  + (((size_t)blockIdx.y * 16 + t) * 512 + cc) * 8;
            else if (tile == 1) gsrc = CP1s + (((size_t)blockIdx.x * 16 + t) * 512 + cc) * 8;
            else                gsrc = CP1s + (((size_t)blockIdx.x * 16 + (t ^ 8)) * 512 + cc) * 8;
            short* ldst = &lds[buf][(is * 256 + wid * 64) * 8];  // wave-uniform base
            __builtin_amdgcn_global_load_lds(
                (const __attribute__((address_space(1))) unsigned int*)gsrc,
                (__attribute__((address_space(3))) unsigned int*)ldst,
                16, 0, 0);
        }
    };

    STAGE(0, 0);
    __syncthreads();

    int kc = lane >> 4;       // k-chunk 0..3
    int lr = lane & 15;

    for (int t = 0; t < NST; ++t) {
        if (t + 1 < NST) STAGE((t + 1) & 1, t + 1);
        const short* At  = &lds[t & 1][0];
        const short* B1t = &lds[t & 1][4096];
        const short* B2t = &lds[t & 1][8192];
        bf16x8 af[4], b1f[4], b2f[4];
        #pragma unroll
        for (int i = 0; i < 4; ++i) {
            af[i]  = *(const bf16x8*)(At  + ((size_t)kc * 128 + wrow * 64 + i * 16 + lr) * 8);
            b1f[i] = *(const bf16x8*)(B1t + ((size_t)kc * 128 + wcol * 64 + i * 16 + lr) * 8);
            b2f[i] = *(const bf16x8*)(B2t + ((size_t)kc * 128 + wcol * 64 + i * 16 + lr) * 8);
        }
        #pragma unroll
        for (int i = 0; i < 4; ++i)
            #pragma unroll
            for (int j = 0; j < 4; ++j) {
                acc[i][j] = __builtin_amdgcn_mfma_f32_16x16x32_bf16(af[i], b1f[j], acc[i][j], 0, 0, 0);
                acc[i][j] = __builtin_amdgcn_mfma_f32_16x16x32_bf16(af[i], b2f[j], acc[i][j], 0, 0, 0);
            }
        __syncthreads();
    }

    // C/D layout: col = lane&15, row = (lane>>4)*4 + reg
    #pragma unroll
    for (int i = 0; i < 4; ++i) {
        int row0 = bm0 + wrow * 64 + i * 16 + (lane >> 4) * 4;
        #pragma unroll
        for (int j = 0; j < 4; ++j) {
            int col = bn0 + wcol * 64 + j * 16 + (lane & 15);
            float cs = csq[col];
            #pragma unroll
            for (int r = 0; r < 4; ++r) {
                float xs = xsq[row0 + r];
                Dist[(size_t)(row0 + r) * K_ + col] = xs + cs - 2.f * acc[i][j][r];
            }
        }
    }
}

// ---------------- fp32 fallback distance GEMM (proven R2 kernel) ----------------
#define BM 128
#define BN 128
#define BK 16
__global__ __launch_bounds__(256, 4) void dist_gemm(
        const float* __restrict__ X, const float* __restrict__ C,
        const float* __restrict__ xsq, const float* __restrict__ csq,
        float* __restrict__ Dist) {
    __shared__ float As[BK][BM + 4];
    __shared__ float Bs[BK][BN + 4];
    int tid = threadIdx.x;
    int tx = tid & 15, ty = tid >> 4;
    int bm0 = blockIdx.y * BM, bn0 = blockIdx.x * BN;
    int r = tid & 127;
    const float* src = (tid < 128) ? (X + (size_t)(bm0 + r) * D_)
                                   : (C + (size_t)(bn0 + r) * D_);
    float* dst = (tid < 128) ? &As[0][0] : &Bs[0][0];
    float acc[2][2][4][4] = {};
    float4 p0 = *reinterpret_cast<const float4*>(src + 0);
    float4 p1 = *reinterpret_cast<const float4*>(src + 4);
    float4 p2 = *reinterpret_cast<const float4*>(src + 8);
    float4 p3 = *reinterpret_cast<const float4*>(src + 12);
    for (int t = 0; t < D_ / BK; ++t) {
        __syncthreads();
        dst[ 0*(BM+4) + r] = p0.x; dst[ 1*(BM+4) + r] = p0.y;
        dst[ 2*(BM+4) + r] = p0.z; dst[ 3*(BM+4) + r] = p0.w;
        dst[ 4*(BM+4) + r] = p1.x; dst[ 5*(BM+4) + r] = p1.y;
        dst[ 6*(BM+4) + r] = p1.z; dst[ 7*(BM+4) + r] = p1.w;
        dst[ 8*(BM+4) + r] = p2.x; dst[ 9*(BM+4) + r] = p2.y;
        dst[10*(BM+4) + r] = p2.z; dst[11*(BM+4) + r] = p2.w;
        dst[12*(BM+4) + r] = p3.x; dst[13*(BM+4) + r] = p3.y;
        dst[14*(BM+4) + r] = p3.z; dst[15*(BM+4) + r] = p3.w;
        __syncthreads();
        if (t < D_ / BK - 1) {
            const float* s2 = src + (t + 1) * BK;
            p0 = *reinterpret_cast<const float4*>(s2 + 0);
            p1 = *reinterpret_cast<const float4*>(s2 + 4);
            p2 = *reinterpret_cast<const float4*>(s2 + 8);
            p3 = *reinterpret_cast<const float4*>(s2 + 12);
        }
        #pragma unroll
        for (int kk = 0; kk < BK; ++kk) {
            float4 a0 = *reinterpret_cast<const float4*>(&As[kk][ty * 4]);
            float4 a1 = *reinterpret_cast<const float4*>(&As[kk][64 + ty * 4]);
            float4 b0 = *reinterpret_cast<const float4*>(&Bs[kk][tx * 4]);
            float4 b1 = *reinterpret_cast<const float4*>(&Bs[kk][64 + tx * 4]);
            float af[2][4] = {{a0.x, a0.y, a0.z, a0.w}, {a1.x, a1.y, a1.z, a1.w}};
            float bf[2][4] = {{b0.x, b0.y, b0.z, b0.w}, {b1.x, b1.y, b1.z, b1.w}};
            #pragma unroll
            for (int rg = 0; rg < 2; ++rg)
                #pragma unroll
                for (int cg = 0; cg < 2; ++cg)
                    #pragma unroll
                    for (int i = 0; i < 4; ++i)
                        #pragma unroll
                        for (int j = 0; j < 4; ++j)
                            acc[rg][cg][i][j] += af[rg][i] * bf[cg][j];
        }
    }
    #pragma unroll
    for (int rg = 0; rg < 2; ++rg)
        #pragma unroll
        for (int i = 0; i < 4; ++i) {
            int row = bm0 + rg * 64 + ty * 4 + i;
            float xs = xsq[row];
            #pragma unroll
            for (int cg = 0; cg < 2; ++cg) {
                int col = bn0 + cg * 64 + tx * 4;
                float4 cs = *reinterpret_cast<const float4*>(csq + col);
                float4 o;
                o.x = xs + cs.x - 2.f * acc[rg][cg][i][0];
                o.y = xs + cs.y - 2.f * acc[rg][cg][i][1];
                o.z = xs + cs.z - 2.f * acc[rg][cg][i][2];
                o.w = xs + cs.w - 2.f * acc[rg][cg][i][3];
                *reinterpret_cast<float4*>(Dist + (size_t)row * K_ + col) = o;
            }
        }
}

// ---------------- fused: softmax + top-2 argmin + exact refine + quantize ----------------
// NO global atomics: per-row ql written to qlrow[] (reduced in finalize).
__global__ __launch_bounds__(256) void softmax_quant(
        float* __restrict__ Dist, const float* __restrict__ X,
        const float* __restrict__ C, float* __restrict__ outq,
        float* __restrict__ probs, float* __restrict__ qlrow) {
    int row = blockIdx.x;
    int t = threadIdx.x;
    int wave = t >> 6, lane = t & 63;
    float* drow = Dist + (size_t)row * K_;

    float v[8];
    float4 v0 = *reinterpret_cast<const float4*>(drow + t * 8);
    float4 v1v = *reinterpret_cast<const float4*>(drow + t * 8 + 4);
    v[0]=v0.x; v[1]=v0.y; v[2]=v0.z; v[3]=v0.w;
    v[4]=v1v.x; v[5]=v1v.y; v[6]=v1v.z; v[7]=v1v.w;

    // per-thread top-2 (ascending index -> first-index tiebreak)
    float v1 = v[0]; int i1 = t * 8;
    float v2 = 3.4e38f; int i2 = 0x7fffffff;
    #pragma unroll
    for (int j = 1; j < 8; ++j) {
        int idx = t * 8 + j;
        if (v[j] < v1) { v2 = v1; i2 = i1; v1 = v[j]; i1 = idx; }
        else if (ltidx(v[j], idx, v2, i2)) { v2 = v[j]; i2 = idx; }
    }
    // wave butterfly top-2 merge
    #pragma unroll
    for (int off = 32; off > 0; off >>= 1) {
        float w1 = __shfl_xor(v1, off, 64); int j1 = __shfl_xor(i1, off, 64);
        float w2 = __shfl_xor(v2, off, 64); int j2 = __shfl_xor(i2, off, 64);
        if (ltidx(w1, j1, v1, i1)) {
            if (ltidx(v1, i1, w2, j2)) { v2 = v1; i2 = i1; }
            else                       { v2 = w2; i2 = j2; }
            v1 = w1; i1 = j1;
        } else if (ltidx(w1, j1, v2, i2)) { v2 = w1; i2 = j1; }
    }
    __shared__ float sv1[4], sv2[4]; __shared__ int si1[4], si2[4];
    __shared__ float ws[4];
    if (lane == 0) { sv1[wave] = v1; si1[wave] = i1; sv2[wave] = v2; si2[wave] = i2; }
    __syncthreads();
    float dmin = sv1[0]; int am = si1[0];
    float d2nd = sv2[0]; int am2 = si2[0];
    #pragma unroll
    for (int w = 1; w < 4; ++w) {
        float w1 = sv1[w]; int j1 = si1[w];
        float w2 = sv2[w]; int j2 = si2[w];
        if (ltidx(w1, j1, dmin, am)) {
            if (ltidx(dmin, am, w2, j2)) { d2nd = dmin; am2 = am; }
            else                         { d2nd = w2;   am2 = j2; }
            dmin = w1; am = j1;
        } else if (ltidx(w1, j1, d2nd, am2)) { d2nd = w1; am2 = j1; }
    }

    // softmax (shift by dmin; constant shift cancels exactly)
    float e[8]; float s = 0.f;
    #pragma unroll
    for (int j = 0; j < 8; ++j) { e[j] = __expf(-100.f * (v[j] - dmin)); s += e[j]; }
    s = waveReduceSum(s);
    if (lane == 0) ws[wave] = s;
    __syncthreads();
    float inv = 1.f / (ws[0] + ws[1] + ws[2] + ws[3]);

    float4 o0 = make_float4(e[0]*inv, e[1]*inv, e[2]*inv, e[3]*inv);
    float4 o1 = make_float4(e[4]*inv, e[5]*inv, e[6]*inv, e[7]*inv);
    *reinterpret_cast<float4*>(drow + t * 8)     = o0;
    *reinterpret_cast<float4*>(drow + t * 8 + 4) = o1;

    // exact fp32 refinement of top-2 + quantize + ql (wave 0)
    if (wave == 0) {
        float4 x  = *reinterpret_cast<const float4*>(X + (size_t)row * D_ + lane * 4);
        float4 c1 = *reinterpret_cast<const float4*>(C + (size_t)am  * D_ + lane * 4);
        float4 c2 = *reinterpret_cast<const float4*>(C + (size_t)am2 * D_ + lane * 4);
        float d1x = (x.x-c1.x)*(x.x-c1.x) + (x.y-c1.y)*(x.y-c1.y)
                  + (x.z-c1.z)*(x.z-c1.z) + (x.w-c1.w)*(x.w-c1.w);
        float d2x = (x.x-c2.x)*(x.x-c2.x) + (x.y-c2.y)*(x.y-c2.y)
                  + (x.z-c2.z)*(x.z-c2.z) + (x.w-c2.w)*(x.w-c2.w);
        d1x = waveReduceSum(d1x);
        d2x = waveReduceSum(d2x);
        bool pick2 = ltidx(d2x, am2, d1x, am);
        float4 q = pick2 ? c2 : c1;
        float dq = pick2 ? d2x : d1x;
        *reinterpret_cast<float4*>(outq + (size_t)row * D_ + lane * 4) = q;
        if (lane == 0) {
            qlrow[row] = dq;
            probs[row] = 1.0f / (float)K_;
        }
    }
}

// ---------------- finalize: reduce arrays + scalars (single block) ----------------
__global__ __launch_bounds__(256) void finalize_kernel(
        const double* __restrict__ acc, const float* __restrict__ xsq,
        const float* __restrict__ qlrow, const float* __restrict__ cspart,
        float* __restrict__ o) {
    int t = threadIdx.x;
    double xs = 0.0, ql = 0.0, cs = 0.0;
    for (int i = t; i < R_; i += 256) { xs += (double)xsq[i]; ql += (double)qlrow[i]; }
    if (t < 64) cs = (double)cspart[t];
    __shared__ double r0[256], r1[256], r2[256];
    r0[t] = xs; r1[t] = ql; r2[t] = cs;
    __syncthreads();
    for (int off = 128; off > 0; off >>= 1) {
        if (t < off) { r0[t] += r0[t+off]; r1[t] += r1[t+off]; r2[t] += r2[t+off]; }
        __syncthreads();
    }
    if (t == 0) {
        o[0] = (float)(r1[0] / (double)R_);                                  // quantization_loss
        o[1] = (float)(acc[3] / (double)K_);                                 // uselessness
        o[2] = (float)(2.0 * r0[0] / (double)R_
                     - 2.0 * r2[0] / ((double)B_ * (double)B_ * (double)A_)); // latent_diversity
    }
}

extern "C" void kernel_launch(void* const* d_in, const int* in_sizes, int n_in,
                              void* d_out, int out_size, void* d_ws, size_t ws_size,
                              hipStream_t stream) {
    const float* X  = (const float*)d_in[0];
    const float* C  = (const float*)d_in[1];
    const float* W  = (const float*)d_in[2];
    const int*   RI = (const int*)d_in[3];

    float* out    = (float*)d_out;
    float* out_q  = out;                         // R_*D_ floats (8 MB)
    float* out_p  = out_q + (size_t)R_ * D_;     // R_
    float* out_s  = out_p + R_;                  // R_*K_ (dist scratch -> soft_one_hot)
    float* out_sc = out_s + (size_t)R_ * K_;     // 3 scalars

    char* wsb = (char*)d_ws;
    double* acc   = (double*)wsb;                               // 8 doubles (64 B)
    float*  xsq   = (float*)(wsb + 64);                         // R_ floats
    float*  csq   = (float*)(wsb + 64 + R_*4);                  // K_ floats
    float*  qlrow = (float*)(wsb + 64 + R_*4 + K_*4);           // R_ floats
    float*  cspart= (float*)(wsb + 64 + R_*4 + K_*4 + R_*4);    // 64 floats
    short*  CP1s  = (short*)(wsb + 64 + R_*4 + K_*4 + R_*4 + 256); // K_*KEFF shorts (2 MB)

    const size_t WS_NEEDED = 64 + (size_t)R_*4 + (size_t)K_*4 + (size_t)R_*4 + 256
                           + (size_t)K_*KEFF*2;

    hipMemsetAsync(d_ws, 0, 64, stream);

    hipLaunchKernelGGL(col_sum_sq, dim3((A_*D_)/256), dim3(256), 0, stream, X, cspart);
    hipLaunchKernelGGL(wsum_kernel, dim3(1), dim3(256), 0, stream, W, acc);
    hipLaunchKernelGGL(useless_kernel, dim3(K_/4), dim3(256), 0, stream, X, C, W, RI, acc, acc + 3);

    if (ws_size >= WS_NEEDED) {
        short* XPs = (short*)out_q;   // staged in out_q region, consumed before overwrite
        hipLaunchKernelGGL(convertX, dim3(R_/4), dim3(256), 0, stream, X, XPs, xsq);
        hipLaunchKernelGGL(convertC, dim3(K_/4), dim3(256), 0, stream, C, CP1s, csq);
        hipLaunchKernelGGL(dist_mfma, dim3(K_/128, R_/128), dim3(256), 0, stream,
                           XPs, CP1s, xsq, csq, out_s);
    } else {
        hipLaunchKernelGGL(row_sqnorm, dim3(R_/4), dim3(256), 0, stream, X, xsq, R_);
        hipLaunchKernelGGL(row_sqnorm, dim3(K_/4), dim3(256), 0, stream, C, csq, K_);
        hipLaunchKernelGGL(dist_gemm, dim3(K_/BN, R_/BM), dim3(256), 0, stream, X, C, xsq, csq, out_s);
    }

    hipLaunchKernelGGL(softmax_quant, dim3(R_), dim3(256), 0, stream, out_s, X, C, out_q, out_p, qlrow);
    hipLaunchKernelGGL(finalize_kernel, dim3(1), dim3(256), 0, stream, acc, xsq, qlrow, cspart, out_sc);
}